// Round 5
// baseline (441.394 us; speedup 1.0000x reference)
//
#include <hip/hip_runtime.h>
#include <hip/hip_bf16.h>

// Shapes fixed by the reference
#define T_TOK 4096
#define I1    512
#define O1    2049
#define O1P   2176        // padded N1 rows (17*128)
#define K1    4608        // 8*512 spline + 512 silu (= 576 groups, no pad)
#define NG1   576         // K1/8
#define I2    2049
#define O2    512
#define K2P   18496       // 8*2049 spline + 257 silu(+guard) + 6 pad groups = 2312*8 = 289*64
#define NG2   2312        // K2P/8
#define HLD   2176        // H row stride (floats)
#define SPLITS2 8
#define KLEN2 2368        // 37*64; slice 7 clamps to 30 tiles (16576..18496)
#define NBY   32          // T_TOK/128, both layers
#define PW1_NB 4896       // (2176*576)/256
#define E1_NB  9216       // (4096*576)/256
#define PW2_NB 8192       // 512 * 4096slots / 256
#define E2B_NB 8192       // 4096 * 512slots / 256

typedef __attribute__((ext_vector_type(8))) short short8;
typedef __attribute__((ext_vector_type(4))) float floatx4;
typedef __attribute__((address_space(3))) void* lds_ptr_t;
typedef const __attribute__((address_space(1))) void* gmem_ptr_t;

__device__ __forceinline__ unsigned short f2bf(float f) {   // RNE (prep kernels)
  union { __hip_bfloat16 h; unsigned short u; } cv;
  cv.h = __float2bfloat16(f);
  return cv.u;
}
__device__ __forceinline__ unsigned bfr(float f) {          // cheap near-RNE (hot path)
  union { float f; unsigned u; } c; c.f = f;
  return (c.u + 0x8000u) >> 16;
}
__device__ __forceinline__ float silu_f(float x) { return x / (1.0f + __expf(-x)); }

// All 8 cubic-basis slots for one group as 8 bf16 in a uint4 (branchless funnel shift).
__device__ __forceinline__ uint4 spline_pack(float h) {
  float u = (h + 2.2f) * 2.5f;
  int ji = (int)u;
  ji = ji < 0 ? 0 : (ji > 10 ? 10 : ji);
  float t = u - (float)ji;
  float it = 1.0f - t, t2 = t * t, t3 = t2 * t;
  float b0 = it * it * it * (1.0f / 6.0f);
  float b1 = (3.0f * t3 - 6.0f * t2 + 4.0f) * (1.0f / 6.0f);
  float b2 = (-3.0f * t3 + 3.0f * t2 + 3.0f * t + 1.0f) * (1.0f / 6.0f);
  float b3 = t3 * (1.0f / 6.0f);
  unsigned pk01 = bfr(b0) | (bfr(b1) << 16);
  unsigned pk23 = bfr(b2) | (bfr(b3) << 16);
  unsigned long long p64 = (unsigned long long)pk01 | ((unsigned long long)pk23 << 32);
  bool inR = (h >= -2.2f) && (h < 2.2f);
  p64 = inR ? p64 : 0ull;
  int sh = (ji - 3) * 16;
  int shr = sh < 0 ? -sh : 0;
  int shl = sh < 0 ? 0 : sh;
  __uint128_t v = ((__uint128_t)(p64 >> shr)) << shl;
  union { __uint128_t q; uint4 u4; } cv;
  cv.q = v;
  return cv.u4;
}

// prep1: fused pack_w1 + expand1. All stores uint4 (one 8-bf16 group per thread).
//  b <  PW1_NB : W1'[o, g*8..]: g<512 -> sw1[o,g,:]*sc1[o,g]; g>=512 -> bw1 slice; o>=2049 -> 0
//  b >= PW1_NB : A1[m, g*8..]: g<512 -> spline basis of x[m,g]; else silu(x[m,(g-512)*8+c])
__global__ void prep1_kernel(const float* __restrict__ x, const float* __restrict__ bw1,
                             const float* __restrict__ sw1, const float* __restrict__ sc1,
                             unsigned short* __restrict__ A1, unsigned short* __restrict__ W1) {
  int b = blockIdx.x;
  union { unsigned short s[8]; uint4 v; } pk;
  if (b < PW1_NB) {
    int idx = b * 256 + threadIdx.x;
    int o = idx / NG1, g = idx - o * NG1;
    if (o >= O1) {
      pk.v = make_uint4(0u, 0u, 0u, 0u);
    } else if (g < 512) {
      const float4* p = (const float4*)&sw1[(size_t)o * 4096 + g * 8];
      float4 a = p[0], c = p[1];
      float sc = sc1[(size_t)o * I1 + g];
      pk.s[0] = f2bf(a.x * sc); pk.s[1] = f2bf(a.y * sc);
      pk.s[2] = f2bf(a.z * sc); pk.s[3] = f2bf(a.w * sc);
      pk.s[4] = f2bf(c.x * sc); pk.s[5] = f2bf(c.y * sc);
      pk.s[6] = f2bf(c.z * sc); pk.s[7] = f2bf(c.w * sc);
    } else {
      const float4* p = (const float4*)&bw1[(size_t)o * I1 + (g - 512) * 8];
      float4 a = p[0], c = p[1];
      pk.s[0] = f2bf(a.x); pk.s[1] = f2bf(a.y); pk.s[2] = f2bf(a.z); pk.s[3] = f2bf(a.w);
      pk.s[4] = f2bf(c.x); pk.s[5] = f2bf(c.y); pk.s[6] = f2bf(c.z); pk.s[7] = f2bf(c.w);
    }
    *(uint4*)&W1[(size_t)o * K1 + (size_t)g * 8] = pk.v;
  } else {
    int idx = (b - PW1_NB) * 256 + threadIdx.x;
    int m = idx / NG1, g = idx - m * NG1;
    if (g < 512) {
      pk.v = spline_pack(x[(size_t)m * I1 + g]);
    } else {
      const float4* p = (const float4*)&x[(size_t)m * I1 + (size_t)(g - 512) * 8];
      float4 a = p[0], c = p[1];
      pk.s[0] = f2bf(silu_f(a.x)); pk.s[1] = f2bf(silu_f(a.y));
      pk.s[2] = f2bf(silu_f(a.z)); pk.s[3] = f2bf(silu_f(a.w));
      pk.s[4] = f2bf(silu_f(c.x)); pk.s[5] = f2bf(silu_f(c.y));
      pk.s[6] = f2bf(silu_f(c.z)); pk.s[7] = f2bf(silu_f(c.w));
    }
    *(uint4*)&A1[(size_t)m * K1 + (size_t)g * 8] = pk.v;
  }
}

// mid: fused pack_w2 + A2 silu/pad groups (runs after gemm1; spline groups of A2
// were already written by gemm1's fused epilogue).
//  b <  PW2_NB : W2'[o, g*8..]: g<2049 spline_w2*scaler2; g<2305 base_w2 (full);
//                g==2305 base_w2 col 2048 only; g in [2306,2312) -> 0
//  b >= PW2_NB : A2[m, g*8..] for g = 2049+g2: silu(H[m, c0+j]) guarded; pad -> 0
__global__ void mid_kernel(const float* __restrict__ bw2, const float* __restrict__ sw2,
                           const float* __restrict__ sc2, const float* __restrict__ H,
                           unsigned short* __restrict__ W2, unsigned short* __restrict__ A2) {
  int b = blockIdx.x;
  union { unsigned short s[8]; uint4 v; } pk;
  if (b < PW2_NB) {
    int idx = b * 256 + threadIdx.x;
    int o = idx >> 12, g = idx & 4095;
    if (g >= NG2) return;
    if (g < 2049) {
      const float4* p = (const float4*)&sw2[(size_t)o * 16392 + (size_t)g * 8];
      float4 a = p[0], c = p[1];
      float sc = sc2[(size_t)o * I2 + g];
      pk.s[0] = f2bf(a.x * sc); pk.s[1] = f2bf(a.y * sc);
      pk.s[2] = f2bf(a.z * sc); pk.s[3] = f2bf(a.w * sc);
      pk.s[4] = f2bf(c.x * sc); pk.s[5] = f2bf(c.y * sc);
      pk.s[6] = f2bf(c.z * sc); pk.s[7] = f2bf(c.w * sc);
    } else if (g < 2306) {
      int c0 = (g - 2049) * 8;
#pragma unroll
      for (int j = 0; j < 8; ++j) {
        int k = c0 + j;
        pk.s[j] = (k < I2) ? f2bf(bw2[(size_t)o * I2 + k]) : (unsigned short)0;
      }
    } else {
      pk.v = make_uint4(0u, 0u, 0u, 0u);
    }
    *(uint4*)&W2[(size_t)o * K2P + (size_t)g * 8] = pk.v;
  } else {
    int idx = (b - PW2_NB) * 256 + threadIdx.x;
    int m = idx >> 9, g2 = idx & 511;
    if (g2 >= NG2 - 2049) return;
    int g = 2049 + g2;
    if (g < 2306) {
      int c0 = (g - 2049) * 8;
#pragma unroll
      for (int j = 0; j < 8; ++j) {
        int k = c0 + j;
        pk.s[j] = (k < I2) ? f2bf(silu_f(H[(size_t)m * HLD + k])) : (unsigned short)0;
      }
    } else {
      pk.v = make_uint4(0u, 0u, 0u, 0u);
    }
    *(uint4*)&A2[(size_t)m * K2P + (size_t)g * 8] = pk.v;
  }
}

// ---- Pure bf16 GEMM (round-1 proven structure; inner loop untouched) ----
// C = A(MxK) * B(NxK)^T, row-major bf16, staged via global_load_lds w16 with XOR
// chunk pre-swizzle on the GLOBAL source address (linear LDS dest; read side
// applies the same XOR). 128x128 tile, 256 threads = 4 waves, 2-barrier K-loop.
// Multi-block residency (2-4 blocks/CU) provides the stage/compute overlap (m114);
// rounds 2-4 showed deep pipelines and grid rebalances both regress here.
// storeMode 0 (layer 1): store H[m*ldc+n] fp32 AND the fused A2 spline group
//   A2sp[m*K2P + n*8] = spline_pack(h) — per-lane, from the accumulator directly.
// storeMode 2 (layer 2): atomicAdd C[m*ldc+n] (split-K).
__global__ __launch_bounds__(256, 4)
void gemm_bt_kernel(const unsigned short* __restrict__ Aw, const unsigned short* __restrict__ Bw,
                    float* __restrict__ C, unsigned short* __restrict__ A2sp,
                    int Ktot, int N, int ldc, int kLen, int nBx, int storeMode)
{
  __shared__ __align__(16) unsigned short As[128 * 64];
  __shared__ __align__(16) unsigned short Bs[128 * 64];

  // Grid decode: Lb = (p&7) + 8*(bx + nBx*(p>>3)), p = by + NBY*bz
  const int Lb = blockIdx.x;
  const int m8 = Lb & 7;
  const int r  = Lb >> 3;
  const int bx = r % nBx;
  const int p  = m8 + ((r / nBx) << 3);
  const int by = p & (NBY - 1);
  const int bz = p >> 5;                   // NBY = 32

  const int tid = threadIdx.x;
  const int ks = bz * kLen;
  int ke = ks + kLen; if (ke > Ktot) ke = Ktot;

  const int w = tid >> 6, L = tid & 63, q = L >> 4, ln = L & 15;
  const int wm = (w & 1) << 6, wn = (w >> 1) << 6;

  floatx4 zf = {0.f, 0.f, 0.f, 0.f};
  floatx4 acc[4][4];
#pragma unroll
  for (int mt = 0; mt < 4; ++mt)
#pragma unroll
    for (int nt = 0; nt < 4; ++nt)
      acc[mt][nt] = zf;

  // Staging: 4 chunks/thread/operand, lane-contiguous LDS dest (wave-uniform base + lane*16)
  const unsigned short* ga[4];
  const unsigned short* gb[4];
  int ldsOff[4];
#pragma unroll
  for (int r4 = 0; r4 < 4; ++r4) {
    int e = r4 * 256 + tid;
    int br = e >> 3;
    int cg = (e & 7) ^ (br & 7);
    ga[r4] = Aw + ((long)by * 128 + br) * (long)Ktot + ks + cg * 8;
    gb[r4] = Bw + ((long)bx * 128 + br) * (long)Ktot + ks + cg * 8;
    ldsOff[r4] = e * 8;
  }

  for (int kc = ks; kc < ke; kc += 64) {
    __syncthreads();                        // prior MFMA done reading LDS
#pragma unroll
    for (int r4 = 0; r4 < 4; ++r4) {
      __builtin_amdgcn_global_load_lds((gmem_ptr_t)ga[r4], (lds_ptr_t)&As[ldsOff[r4]], 16, 0, 0);
      ga[r4] += 64;
      __builtin_amdgcn_global_load_lds((gmem_ptr_t)gb[r4], (lds_ptr_t)&Bs[ldsOff[r4]], 16, 0, 0);
      gb[r4] += 64;
    }
    __syncthreads();                        // DMA drained (vmcnt(0) at barrier)

#pragma unroll
    for (int s = 0; s < 2; ++s) {
      short8 af[4], bf[4];
#pragma unroll
      for (int mt = 0; mt < 4; ++mt) {
        int rr = wm + mt * 16 + ln;
        int cl = ((s << 2) | q) ^ (rr & 7);
        af[mt] = *(const short8*)&As[rr * 64 + cl * 8];
      }
#pragma unroll
      for (int nt = 0; nt < 4; ++nt) {
        int rr = wn + nt * 16 + ln;
        int cl = ((s << 2) | q) ^ (rr & 7);
        bf[nt] = *(const short8*)&Bs[rr * 64 + cl * 8];
      }
#pragma unroll
      for (int mt = 0; mt < 4; ++mt)
#pragma unroll
        for (int nt = 0; nt < 4; ++nt)
          acc[mt][nt] = __builtin_amdgcn_mfma_f32_16x16x32_bf16(af[mt], bf[nt], acc[mt][nt], 0, 0, 0);
    }
  }

  // Epilogue. D layout: col = lane&15 (n), row = q*4+reg (m)  [m89-verified]
  if (storeMode == 0) {                     // layer 1: H fp32 + fused A2 spline groups
#pragma unroll
    for (int mt = 0; mt < 4; ++mt) {
#pragma unroll
      for (int nt = 0; nt < 4; ++nt) {
        int n = bx * 128 + wn + nt * 16 + ln;
        if (n < N) {
          int m0 = by * 128 + wm + mt * 16 + q * 4;
#pragma unroll
          for (int rg = 0; rg < 4; ++rg) {
            float h = acc[mt][nt][rg];
            C[(size_t)(m0 + rg) * ldc + n] = h;
            *(uint4*)&A2sp[(size_t)(m0 + rg) * K2P + (size_t)n * 8] = spline_pack(h);
          }
        }
      }
    }
  } else {                                  // atomic accumulate (layer 2, split-K)
#pragma unroll
    for (int mt = 0; mt < 4; ++mt) {
#pragma unroll
      for (int nt = 0; nt < 4; ++nt) {
        int n = bx * 128 + wn + nt * 16 + ln;
        if (n < N) {
          int m0 = by * 128 + wm + mt * 16 + q * 4;
#pragma unroll
          for (int rg = 0; rg < 4; ++rg)
            atomicAdd(&C[(size_t)(m0 + rg) * ldc + n], acc[mt][nt][rg]);
        }
      }
    }
  }
}

extern "C" void kernel_launch(void* const* d_in, const int* in_sizes, int n_in,
                              void* d_out, int out_size, void* d_ws, size_t ws_size,
                              hipStream_t stream) {
  const float* x   = (const float*)d_in[0];
  const float* bw1 = (const float*)d_in[1];
  const float* sw1 = (const float*)d_in[2];
  const float* sc1 = (const float*)d_in[3];
  const float* bw2 = (const float*)d_in[4];
  const float* sw2 = (const float*)d_in[5];
  const float* sc2 = (const float*)d_in[6];
  float* out = (float*)d_out;

  // Workspace: H (35.7) | A2 (151.5) | A1 (37.7) | W1 (20.1)  = 245.0 MB
  // W2 (18.9) aliases A1's region — packed by mid_kernel AFTER gemm1 (A1 dead).
  float* H = (float*)d_ws;
  unsigned short* A2 = (unsigned short*)(H + (size_t)T_TOK * HLD);
  unsigned short* A1 = A2 + (size_t)T_TOK * K2P;
  unsigned short* W1 = A1 + (size_t)T_TOK * K1;
  unsigned short* W2 = A1;                               // alias (A1 dead post-gemm1)

  hipMemsetAsync(d_out, 0, (size_t)out_size * sizeof(float), stream);

  // pack_w1 + expand1, one launch
  prep1_kernel<<<PW1_NB + E1_NB, 256, 0, stream>>>(x, bw1, sw1, sc1, A1, W1);

  // Layer 1: H = A1 @ W1'^T (M=4096, N=2049 pad 2176, K=4608), 544 blocks;
  // epilogue also writes A2 spline groups directly from the accumulator.
  gemm_bt_kernel<<<(O1P / 128) * NBY, 256, 0, stream>>>(
      A1, W1, H, A2, K1, O1, HLD, K1, O1P / 128, 0);

  // pack_w2 (into old-A1 region) + A2 silu/pad groups, one launch
  mid_kernel<<<PW2_NB + E2B_NB, 256, 0, stream>>>(bw2, sw2, sc2, H, W2, A2);

  // Layer 2: out += A2 @ W2'^T (M=4096, N=512, K=18496), split-K 8 -> 1024 blocks.
  gemm_bt_kernel<<<(O2 / 128) * NBY * SPLITS2, 256, 0, stream>>>(
      A2, W2, out, nullptr, K2P, O2, O2, KLEN2, O2 / 128, 2);
}

// Round 6
// 438.700 us; speedup vs baseline: 1.0061x; 1.0061x over previous
//
#include <hip/hip_runtime.h>
#include <hip/hip_bf16.h>

// Shapes fixed by the reference
#define T_TOK 4096
#define I1    512
#define O1    2049
#define O1P   2176        // padded N1 rows (17*128)
#define K1    4608        // 8*512 spline + 512 silu (= 576 groups, no pad)
#define NG1   576         // K1/8
#define I2    2049
#define O2    512
#define K2P   18496       // 2312 groups * 8 = 289 K-tiles (trimmed zero pad)
#define NG2   2312        // K2P/8
#define HLD   2176        // H row stride (floats)
#define SPLITS2 8
#define KLEN2 2368        // 37*64; slice 7 clamps to 30 tiles (16576..18496)
#define NBY   32          // T_TOK/128, both layers
#define PW1_NB 4896       // (2176*576)/256
#define E1_NB  9216       // (4096*576)/256
#define PW2_NB 8192       // 512*4096 slots / 256

typedef __attribute__((ext_vector_type(8))) short short8;
typedef __attribute__((ext_vector_type(4))) float floatx4;
typedef __attribute__((address_space(3))) void* lds_ptr_t;
typedef const __attribute__((address_space(1))) void* gmem_ptr_t;

__device__ __forceinline__ unsigned short f2bf(float f) {   // RNE (prep kernels)
  union { __hip_bfloat16 h; unsigned short u; } cv;
  cv.h = __float2bfloat16(f);
  return cv.u;
}
__device__ __forceinline__ unsigned bfr(float f) {          // cheap near-RNE (hot path)
  union { float f; unsigned u; } c; c.f = f;
  return (c.u + 0x8000u) >> 16;
}
__device__ __forceinline__ float silu_f(float x) { return x / (1.0f + __expf(-x)); }

// All 8 cubic-basis slots for one group as 8 bf16 in a uint4 (branchless funnel shift).
__device__ __forceinline__ uint4 spline_pack(float h) {
  float u = (h + 2.2f) * 2.5f;
  int ji = (int)u;
  ji = ji < 0 ? 0 : (ji > 10 ? 10 : ji);
  float t = u - (float)ji;
  float it = 1.0f - t, t2 = t * t, t3 = t2 * t;
  float b0 = it * it * it * (1.0f / 6.0f);
  float b1 = (3.0f * t3 - 6.0f * t2 + 4.0f) * (1.0f / 6.0f);
  float b2 = (-3.0f * t3 + 3.0f * t2 + 3.0f * t + 1.0f) * (1.0f / 6.0f);
  float b3 = t3 * (1.0f / 6.0f);
  unsigned pk01 = bfr(b0) | (bfr(b1) << 16);
  unsigned pk23 = bfr(b2) | (bfr(b3) << 16);
  unsigned long long p64 = (unsigned long long)pk01 | ((unsigned long long)pk23 << 32);
  bool inR = (h >= -2.2f) && (h < 2.2f);
  p64 = inR ? p64 : 0ull;
  int sh = (ji - 3) * 16;
  int shr = sh < 0 ? -sh : 0;
  int shl = sh < 0 ? 0 : sh;
  __uint128_t v = ((__uint128_t)(p64 >> shr)) << shl;
  union { __uint128_t q; uint4 u4; } cv;
  cv.q = v;
  return cv.u4;
}

// prep1: fused pack_w1 + expand1. All stores uint4 (one 8-bf16 group per thread).
//  b <  PW1_NB : W1'[o, g*8..]: g<512 -> sw1[o,g,:]*sc1[o,g]; g>=512 -> bw1 slice; o>=2049 -> 0
//  b >= PW1_NB : A1[m, g*8..]: g<512 -> spline basis of x[m,g]; else silu(x[m,(g-512)*8+c])
__global__ void prep1_kernel(const float* __restrict__ x, const float* __restrict__ bw1,
                             const float* __restrict__ sw1, const float* __restrict__ sc1,
                             unsigned short* __restrict__ A1, unsigned short* __restrict__ W1) {
  int b = blockIdx.x;
  union { unsigned short s[8]; uint4 v; } pk;
  if (b < PW1_NB) {
    int idx = b * 256 + threadIdx.x;
    int o = idx / NG1, g = idx - o * NG1;
    if (o >= O1) {
      pk.v = make_uint4(0u, 0u, 0u, 0u);
    } else if (g < 512) {
      const float4* p = (const float4*)&sw1[(size_t)o * 4096 + g * 8];
      float4 a = p[0], c = p[1];
      float sc = sc1[(size_t)o * I1 + g];
      pk.s[0] = f2bf(a.x * sc); pk.s[1] = f2bf(a.y * sc);
      pk.s[2] = f2bf(a.z * sc); pk.s[3] = f2bf(a.w * sc);
      pk.s[4] = f2bf(c.x * sc); pk.s[5] = f2bf(c.y * sc);
      pk.s[6] = f2bf(c.z * sc); pk.s[7] = f2bf(c.w * sc);
    } else {
      const float4* p = (const float4*)&bw1[(size_t)o * I1 + (g - 512) * 8];
      float4 a = p[0], c = p[1];
      pk.s[0] = f2bf(a.x); pk.s[1] = f2bf(a.y); pk.s[2] = f2bf(a.z); pk.s[3] = f2bf(a.w);
      pk.s[4] = f2bf(c.x); pk.s[5] = f2bf(c.y); pk.s[6] = f2bf(c.z); pk.s[7] = f2bf(c.w);
    }
    *(uint4*)&W1[(size_t)o * K1 + (size_t)g * 8] = pk.v;
  } else {
    int idx = (b - PW1_NB) * 256 + threadIdx.x;
    int m = idx / NG1, g = idx - m * NG1;
    if (g < 512) {
      pk.v = spline_pack(x[(size_t)m * I1 + g]);
    } else {
      const float4* p = (const float4*)&x[(size_t)m * I1 + (size_t)(g - 512) * 8];
      float4 a = p[0], c = p[1];
      pk.s[0] = f2bf(silu_f(a.x)); pk.s[1] = f2bf(silu_f(a.y));
      pk.s[2] = f2bf(silu_f(a.z)); pk.s[3] = f2bf(silu_f(a.w));
      pk.s[4] = f2bf(silu_f(c.x)); pk.s[5] = f2bf(silu_f(c.y));
      pk.s[6] = f2bf(silu_f(c.z)); pk.s[7] = f2bf(silu_f(c.w));
    }
    *(uint4*)&A1[(size_t)m * K1 + (size_t)g * 8] = pk.v;
  }
}

// pack_w2: W2'[o, g*8..] as uint4 groups at K2P stride.
//  g<2049: spline_w2*scaler2 (float4 loads); 2049<=g<2306: base_w2 slice (k<I2 guard);
//  2306<=g<2312: zeros.
__global__ void pack_w2_kernel(const float* __restrict__ bw2, const float* __restrict__ sw2,
                               const float* __restrict__ sc2, unsigned short* __restrict__ W2) {
  int idx = blockIdx.x * 256 + threadIdx.x;
  int o = idx >> 12, g = idx & 4095;
  if (g >= NG2) return;
  union { unsigned short s[8]; uint4 v; } pk;
  if (g < 2049) {
    const float4* p = (const float4*)&sw2[(size_t)o * 16392 + (size_t)g * 8];
    float4 a = p[0], c = p[1];
    float sc = sc2[(size_t)o * I2 + g];
    pk.s[0] = f2bf(a.x * sc); pk.s[1] = f2bf(a.y * sc);
    pk.s[2] = f2bf(a.z * sc); pk.s[3] = f2bf(a.w * sc);
    pk.s[4] = f2bf(c.x * sc); pk.s[5] = f2bf(c.y * sc);
    pk.s[6] = f2bf(c.z * sc); pk.s[7] = f2bf(c.w * sc);
  } else if (g < 2306) {
    int c0 = (g - 2049) * 8;
#pragma unroll
    for (int j = 0; j < 8; ++j) {
      int k = c0 + j;
      pk.s[j] = (k < I2) ? f2bf(bw2[(size_t)o * I2 + k]) : (unsigned short)0;
    }
  } else {
    pk.v = make_uint4(0u, 0u, 0u, 0u);
  }
  *(uint4*)&W2[(size_t)o * K2P + (size_t)g * 8] = pk.v;
}

// expand2: A2[m, g*8..] from H (row stride HLD).
//  g<2049 -> spline basis of H[m,g]; 2049<=g<2306 -> silu(H[m,c0+j]) guarded; else 0.
__global__ void expand2_kernel(const float* __restrict__ H, unsigned short* __restrict__ A) {
  int g = blockIdx.x * 256 + threadIdx.x;
  if (g >= NG2) return;
  int m = blockIdx.y;
  uint4 val;
  if (g < 2049) {
    val = spline_pack(H[(size_t)m * HLD + g]);
  } else if (g < 2306) {
    int c0 = (g - 2049) * 8;
    union { unsigned short s[8]; uint4 v; } pk;
#pragma unroll
    for (int c = 0; c < 8; ++c) {
      int idx = c0 + c;
      float v = 0.0f;
      if (idx < I2) v = silu_f(H[(size_t)m * HLD + idx]);
      pk.s[c] = f2bf(v);
    }
    val = pk.v;
  } else {
    val = make_uint4(0u, 0u, 0u, 0u);
  }
  *(uint4*)(A + (size_t)m * K2P + (size_t)g * 8) = val;
}

// ---- Pure bf16 GEMM (round-1 proven structure; best measured 112 us/layer) ----
// C = A(MxK) * B(NxK)^T, row-major bf16, staged via global_load_lds w16 with XOR
// chunk pre-swizzle on the GLOBAL source address (linear LDS dest; read side
// applies the same XOR). 128x128 tile, 256 threads = 4 waves, 2-barrier K-loop.
// Multi-block residency (2-4 blocks/CU) provides the stage/compute overlap (m114);
// rounds 2-4 showed deep pipelines and grid rebalances both regress here; round 5
// showed epilogue fusion serializes (writes burst after the K-loop).
// storeMode 0: plain C[m*ldc+n] store (layer 1 -> H). 2: atomicAdd (layer 2 split-K).
__global__ __launch_bounds__(256, 4)
void gemm_bt_kernel(const unsigned short* __restrict__ Aw, const unsigned short* __restrict__ Bw,
                    float* __restrict__ C, int Ktot, int N, int ldc, int kLen,
                    int nBx, int storeMode)
{
  __shared__ __align__(16) unsigned short As[128 * 64];
  __shared__ __align__(16) unsigned short Bs[128 * 64];

  // Grid decode: Lb = (p&7) + 8*(bx + nBx*(p>>3)), p = by + NBY*bz
  const int Lb = blockIdx.x;
  const int m8 = Lb & 7;
  const int r  = Lb >> 3;
  const int bx = r % nBx;
  const int p  = m8 + ((r / nBx) << 3);
  const int by = p & (NBY - 1);
  const int bz = p >> 5;                   // NBY = 32

  const int tid = threadIdx.x;
  const int ks = bz * kLen;
  int ke = ks + kLen; if (ke > Ktot) ke = Ktot;

  const int w = tid >> 6, L = tid & 63, q = L >> 4, ln = L & 15;
  const int wm = (w & 1) << 6, wn = (w >> 1) << 6;

  floatx4 zf = {0.f, 0.f, 0.f, 0.f};
  floatx4 acc[4][4];
#pragma unroll
  for (int mt = 0; mt < 4; ++mt)
#pragma unroll
    for (int nt = 0; nt < 4; ++nt)
      acc[mt][nt] = zf;

  // Staging: 4 chunks/thread/operand, lane-contiguous LDS dest (wave-uniform base + lane*16)
  const unsigned short* ga[4];
  const unsigned short* gb[4];
  int ldsOff[4];
#pragma unroll
  for (int r4 = 0; r4 < 4; ++r4) {
    int e = r4 * 256 + tid;
    int br = e >> 3;
    int cg = (e & 7) ^ (br & 7);
    ga[r4] = Aw + ((long)by * 128 + br) * (long)Ktot + ks + cg * 8;
    gb[r4] = Bw + ((long)bx * 128 + br) * (long)Ktot + ks + cg * 8;
    ldsOff[r4] = e * 8;
  }

  for (int kc = ks; kc < ke; kc += 64) {
    __syncthreads();                        // prior MFMA done reading LDS
#pragma unroll
    for (int r4 = 0; r4 < 4; ++r4) {
      __builtin_amdgcn_global_load_lds((gmem_ptr_t)ga[r4], (lds_ptr_t)&As[ldsOff[r4]], 16, 0, 0);
      ga[r4] += 64;
      __builtin_amdgcn_global_load_lds((gmem_ptr_t)gb[r4], (lds_ptr_t)&Bs[ldsOff[r4]], 16, 0, 0);
      gb[r4] += 64;
    }
    __syncthreads();                        // DMA drained (vmcnt(0) at barrier)

#pragma unroll
    for (int s = 0; s < 2; ++s) {
      short8 af[4], bf[4];
#pragma unroll
      for (int mt = 0; mt < 4; ++mt) {
        int rr = wm + mt * 16 + ln;
        int cl = ((s << 2) | q) ^ (rr & 7);
        af[mt] = *(const short8*)&As[rr * 64 + cl * 8];
      }
#pragma unroll
      for (int nt = 0; nt < 4; ++nt) {
        int rr = wn + nt * 16 + ln;
        int cl = ((s << 2) | q) ^ (rr & 7);
        bf[nt] = *(const short8*)&Bs[rr * 64 + cl * 8];
      }
#pragma unroll
      for (int mt = 0; mt < 4; ++mt)
#pragma unroll
        for (int nt = 0; nt < 4; ++nt)
          acc[mt][nt] = __builtin_amdgcn_mfma_f32_16x16x32_bf16(af[mt], bf[nt], acc[mt][nt], 0, 0, 0);
    }
  }

  // Epilogue. D layout: col = lane&15 (n), row = q*4+reg (m)  [m89-verified]
  if (storeMode == 0) {                     // plain row-major store (layer 1 -> H)
#pragma unroll
    for (int mt = 0; mt < 4; ++mt) {
#pragma unroll
      for (int nt = 0; nt < 4; ++nt) {
        int n = bx * 128 + wn + nt * 16 + ln;
        if (n < N) {
          int m0 = by * 128 + wm + mt * 16 + q * 4;
#pragma unroll
          for (int rg = 0; rg < 4; ++rg)
            C[(size_t)(m0 + rg) * ldc + n] = acc[mt][nt][rg];
        }
      }
    }
  } else {                                  // atomic accumulate (layer 2, split-K)
#pragma unroll
    for (int mt = 0; mt < 4; ++mt) {
#pragma unroll
      for (int nt = 0; nt < 4; ++nt) {
        int n = bx * 128 + wn + nt * 16 + ln;
        if (n < N) {
          int m0 = by * 128 + wm + mt * 16 + q * 4;
#pragma unroll
          for (int rg = 0; rg < 4; ++rg)
            atomicAdd(&C[(size_t)(m0 + rg) * ldc + n], acc[mt][nt][rg]);
        }
      }
    }
  }
}

extern "C" void kernel_launch(void* const* d_in, const int* in_sizes, int n_in,
                              void* d_out, int out_size, void* d_ws, size_t ws_size,
                              hipStream_t stream) {
  const float* x   = (const float*)d_in[0];
  const float* bw1 = (const float*)d_in[1];
  const float* sw1 = (const float*)d_in[2];
  const float* sc1 = (const float*)d_in[3];
  const float* bw2 = (const float*)d_in[4];
  const float* sw2 = (const float*)d_in[5];
  const float* sc2 = (const float*)d_in[6];
  float* out = (float*)d_out;

  // Workspace: H (35.7) | A2 (151.5) | A1 (37.7) | W1 (20.1)  = 245.0 MB (R5-verified size)
  // W2 (18.9) aliases A1's region — packed AFTER gemm1 (A1 dead).
  float* H = (float*)d_ws;
  unsigned short* A2 = (unsigned short*)(H + (size_t)T_TOK * HLD);
  unsigned short* A1 = A2 + (size_t)T_TOK * K2P;
  unsigned short* W1 = A1 + (size_t)T_TOK * K1;
  unsigned short* W2 = A1;                               // alias (A1 dead post-gemm1)

  hipMemsetAsync(d_out, 0, (size_t)out_size * sizeof(float), stream);

  // pack_w1 + expand1, one launch (vectorized loads, uint4 stores)
  prep1_kernel<<<PW1_NB + E1_NB, 256, 0, stream>>>(x, bw1, sw1, sc1, A1, W1);

  // Layer 1: H = A1 @ W1'^T. M=4096, N=2049 (rows pad 2176), K=4608. 544 blocks.
  gemm_bt_kernel<<<(O1P / 128) * NBY, 256, 0, stream>>>(
      A1, W1, H, K1, O1, HLD, K1, O1P / 128, 0);

  // A2 from H (H is L2/L3-warm right after gemm1)
  expand2_kernel<<<dim3((NG2 + 255) / 256, T_TOK), 256, 0, stream>>>(H, A2);

  // W2 into old-A1 region (A1 dead); W2 L2-warm for gemm2
  pack_w2_kernel<<<PW2_NB, 256, 0, stream>>>(bw2, sw2, sc2, W2);

  // Layer 2: out += A2 @ W2'^T. M=4096, N=512, K=18496, split-K 8 -> 1024 blocks.
  gemm_bt_kernel<<<(O2 / 128) * NBY * SPLITS2, 256, 0, stream>>>(
      A2, W2, out, K2P, O2, O2, KLEN2, O2 / 128, 2);
}

// Round 7
// 415.325 us; speedup vs baseline: 1.0628x; 1.0563x over previous
//
#include <hip/hip_runtime.h>
#include <hip/hip_bf16.h>

// Shapes fixed by the reference
#define T_TOK 4096
#define I1    512
#define O1    2049
#define O1P   2176        // padded N1 rows (17*128)
#define K1    4608        // 8*512 spline + 512 silu (= 576 groups, no pad)
#define NG1   576         // K1/8
#define I2    2049
#define O2    512
#define K2P   18496       // 2312 groups * 8 = 289 K-tiles (trimmed zero pad)
#define NG2   2312        // K2P/8
#define HLD   2176        // H row stride (floats)
#define SPLITS2 8
#define KLEN2 2368        // 37*64; slice 7 clamps to 30 tiles (16576..18496)
#define NBY   32          // T_TOK/128, both layers
#define PW1_NB 4896       // (2176*576)/256
#define E1_NB  9216       // (4096*576)/256
#define PW2_NB 8192       // 512*4096 slots / 256

typedef __attribute__((ext_vector_type(8))) short short8;
typedef __attribute__((ext_vector_type(4))) float floatx4;
typedef __attribute__((address_space(3))) void* lds_ptr_t;
typedef const __attribute__((address_space(1))) void* gmem_ptr_t;

__device__ __forceinline__ unsigned short f2bf(float f) {   // RNE (prep kernels)
  union { __hip_bfloat16 h; unsigned short u; } cv;
  cv.h = __float2bfloat16(f);
  return cv.u;
}
__device__ __forceinline__ unsigned bfr(float f) {          // cheap near-RNE (hot path)
  union { float f; unsigned u; } c; c.f = f;
  return (c.u + 0x8000u) >> 16;
}
__device__ __forceinline__ float silu_f(float x) { return x / (1.0f + __expf(-x)); }

// All 8 cubic-basis slots for one group as 8 bf16 in a uint4 (branchless funnel shift).
__device__ __forceinline__ uint4 spline_pack(float h) {
  float u = (h + 2.2f) * 2.5f;
  int ji = (int)u;
  ji = ji < 0 ? 0 : (ji > 10 ? 10 : ji);
  float t = u - (float)ji;
  float it = 1.0f - t, t2 = t * t, t3 = t2 * t;
  float b0 = it * it * it * (1.0f / 6.0f);
  float b1 = (3.0f * t3 - 6.0f * t2 + 4.0f) * (1.0f / 6.0f);
  float b2 = (-3.0f * t3 + 3.0f * t2 + 3.0f * t + 1.0f) * (1.0f / 6.0f);
  float b3 = t3 * (1.0f / 6.0f);
  unsigned pk01 = bfr(b0) | (bfr(b1) << 16);
  unsigned pk23 = bfr(b2) | (bfr(b3) << 16);
  unsigned long long p64 = (unsigned long long)pk01 | ((unsigned long long)pk23 << 32);
  bool inR = (h >= -2.2f) && (h < 2.2f);
  p64 = inR ? p64 : 0ull;
  int sh = (ji - 3) * 16;
  int shr = sh < 0 ? -sh : 0;
  int shl = sh < 0 ? 0 : sh;
  __uint128_t v = ((__uint128_t)(p64 >> shr)) << shl;
  union { __uint128_t q; uint4 u4; } cv;
  cv.q = v;
  return cv.u4;
}

// prep1: fused pack_w1 + expand1. All stores uint4 (one 8-bf16 group per thread).
//  b <  PW1_NB : W1'[o, g*8..]: g<512 -> sw1[o,g,:]*sc1[o,g]; g>=512 -> bw1 slice; o>=2049 -> 0
//  b >= PW1_NB : A1[m, g*8..]: g<512 -> spline basis of x[m,g]; else silu(x[m,(g-512)*8+c])
__global__ void prep1_kernel(const float* __restrict__ x, const float* __restrict__ bw1,
                             const float* __restrict__ sw1, const float* __restrict__ sc1,
                             unsigned short* __restrict__ A1, unsigned short* __restrict__ W1) {
  int b = blockIdx.x;
  union { unsigned short s[8]; uint4 v; } pk;
  if (b < PW1_NB) {
    int idx = b * 256 + threadIdx.x;
    int o = idx / NG1, g = idx - o * NG1;
    if (o >= O1) {
      pk.v = make_uint4(0u, 0u, 0u, 0u);
    } else if (g < 512) {
      const float4* p = (const float4*)&sw1[(size_t)o * 4096 + g * 8];
      float4 a = p[0], c = p[1];
      float sc = sc1[(size_t)o * I1 + g];
      pk.s[0] = f2bf(a.x * sc); pk.s[1] = f2bf(a.y * sc);
      pk.s[2] = f2bf(a.z * sc); pk.s[3] = f2bf(a.w * sc);
      pk.s[4] = f2bf(c.x * sc); pk.s[5] = f2bf(c.y * sc);
      pk.s[6] = f2bf(c.z * sc); pk.s[7] = f2bf(c.w * sc);
    } else {
      const float4* p = (const float4*)&bw1[(size_t)o * I1 + (g - 512) * 8];
      float4 a = p[0], c = p[1];
      pk.s[0] = f2bf(a.x); pk.s[1] = f2bf(a.y); pk.s[2] = f2bf(a.z); pk.s[3] = f2bf(a.w);
      pk.s[4] = f2bf(c.x); pk.s[5] = f2bf(c.y); pk.s[6] = f2bf(c.z); pk.s[7] = f2bf(c.w);
    }
    *(uint4*)&W1[(size_t)o * K1 + (size_t)g * 8] = pk.v;
  } else {
    int idx = (b - PW1_NB) * 256 + threadIdx.x;
    int m = idx / NG1, g = idx - m * NG1;
    if (g < 512) {
      pk.v = spline_pack(x[(size_t)m * I1 + g]);
    } else {
      const float4* p = (const float4*)&x[(size_t)m * I1 + (size_t)(g - 512) * 8];
      float4 a = p[0], c = p[1];
      pk.s[0] = f2bf(silu_f(a.x)); pk.s[1] = f2bf(silu_f(a.y));
      pk.s[2] = f2bf(silu_f(a.z)); pk.s[3] = f2bf(silu_f(a.w));
      pk.s[4] = f2bf(silu_f(c.x)); pk.s[5] = f2bf(silu_f(c.y));
      pk.s[6] = f2bf(silu_f(c.z)); pk.s[7] = f2bf(silu_f(c.w));
    }
    *(uint4*)&A1[(size_t)m * K1 + (size_t)g * 8] = pk.v;
  }
}

// pack_w2: W2'[o, g*8..] as uint4 groups at K2P stride.
//  g<2049: spline_w2*scaler2 (float4 loads); 2049<=g<2306: base_w2 slice (k<I2 guard);
//  2306<=g<2312: zeros.
__global__ void pack_w2_kernel(const float* __restrict__ bw2, const float* __restrict__ sw2,
                               const float* __restrict__ sc2, unsigned short* __restrict__ W2) {
  int idx = blockIdx.x * 256 + threadIdx.x;
  int o = idx >> 12, g = idx & 4095;
  if (g >= NG2) return;
  union { unsigned short s[8]; uint4 v; } pk;
  if (g < 2049) {
    const float4* p = (const float4*)&sw2[(size_t)o * 16392 + (size_t)g * 8];
    float4 a = p[0], c = p[1];
    float sc = sc2[(size_t)o * I2 + g];
    pk.s[0] = f2bf(a.x * sc); pk.s[1] = f2bf(a.y * sc);
    pk.s[2] = f2bf(a.z * sc); pk.s[3] = f2bf(a.w * sc);
    pk.s[4] = f2bf(c.x * sc); pk.s[5] = f2bf(c.y * sc);
    pk.s[6] = f2bf(c.z * sc); pk.s[7] = f2bf(c.w * sc);
  } else if (g < 2306) {
    int c0 = (g - 2049) * 8;
#pragma unroll
    for (int j = 0; j < 8; ++j) {
      int k = c0 + j;
      pk.s[j] = (k < I2) ? f2bf(bw2[(size_t)o * I2 + k]) : (unsigned short)0;
    }
  } else {
    pk.v = make_uint4(0u, 0u, 0u, 0u);
  }
  *(uint4*)&W2[(size_t)o * K2P + (size_t)g * 8] = pk.v;
}

// expand2: A2[m, g*8..] from H (row stride HLD).
//  g<2049 -> spline basis of H[m,g]; 2049<=g<2306 -> silu(H[m,c0+j]) guarded; else 0.
__global__ void expand2_kernel(const float* __restrict__ H, unsigned short* __restrict__ A) {
  int g = blockIdx.x * 256 + threadIdx.x;
  if (g >= NG2) return;
  int m = blockIdx.y;
  uint4 val;
  if (g < 2049) {
    val = spline_pack(H[(size_t)m * HLD + g]);
  } else if (g < 2306) {
    int c0 = (g - 2049) * 8;
    union { unsigned short s[8]; uint4 v; } pk;
#pragma unroll
    for (int c = 0; c < 8; ++c) {
      int idx = c0 + c;
      float v = 0.0f;
      if (idx < I2) v = silu_f(H[(size_t)m * HLD + idx]);
      pk.s[c] = f2bf(v);
    }
    val = pk.v;
  } else {
    val = make_uint4(0u, 0u, 0u, 0u);
  }
  *(uint4*)(A + (size_t)m * K2P + (size_t)g * 8) = val;
}

// ---- Pure bf16 GEMM (round-1 proven structure; best measured 112 us/layer) ----
// C = A(MxK) * B(NxK)^T, row-major bf16, staged via global_load_lds w16 with XOR
// chunk pre-swizzle on the GLOBAL source address (linear LDS dest; read side
// applies the same XOR). 128x128 tile, 256 threads = 4 waves, 2-barrier K-loop.
// Multi-block residency (2-4 blocks/CU) provides the stage/compute overlap (m114);
// rounds 2-4 showed deep pipelines and grid rebalances both regress here; round 5
// showed epilogue fusion serializes; round 6 showed launch ORDER controls L3
// residency of A2 (pack_w2 between expand2 and gemm2 cost +89 MB fetch, +20 us).
// storeMode 0: plain C[m*ldc+n] store (layer 1 -> H). 2: atomicAdd (layer 2 split-K).
__global__ __launch_bounds__(256, 4)
void gemm_bt_kernel(const unsigned short* __restrict__ Aw, const unsigned short* __restrict__ Bw,
                    float* __restrict__ C, int Ktot, int N, int ldc, int kLen,
                    int nBx, int storeMode)
{
  __shared__ __align__(16) unsigned short As[128 * 64];
  __shared__ __align__(16) unsigned short Bs[128 * 64];

  // Grid decode: Lb = (p&7) + 8*(bx + nBx*(p>>3)), p = by + NBY*bz
  const int Lb = blockIdx.x;
  const int m8 = Lb & 7;
  const int r  = Lb >> 3;
  const int bx = r % nBx;
  const int p  = m8 + ((r / nBx) << 3);
  const int by = p & (NBY - 1);
  const int bz = p >> 5;                   // NBY = 32

  const int tid = threadIdx.x;
  const int ks = bz * kLen;
  int ke = ks + kLen; if (ke > Ktot) ke = Ktot;

  const int w = tid >> 6, L = tid & 63, q = L >> 4, ln = L & 15;
  const int wm = (w & 1) << 6, wn = (w >> 1) << 6;

  floatx4 zf = {0.f, 0.f, 0.f, 0.f};
  floatx4 acc[4][4];
#pragma unroll
  for (int mt = 0; mt < 4; ++mt)
#pragma unroll
    for (int nt = 0; nt < 4; ++nt)
      acc[mt][nt] = zf;

  // Staging: 4 chunks/thread/operand, lane-contiguous LDS dest (wave-uniform base + lane*16)
  const unsigned short* ga[4];
  const unsigned short* gb[4];
  int ldsOff[4];
#pragma unroll
  for (int r4 = 0; r4 < 4; ++r4) {
    int e = r4 * 256 + tid;
    int br = e >> 3;
    int cg = (e & 7) ^ (br & 7);
    ga[r4] = Aw + ((long)by * 128 + br) * (long)Ktot + ks + cg * 8;
    gb[r4] = Bw + ((long)bx * 128 + br) * (long)Ktot + ks + cg * 8;
    ldsOff[r4] = e * 8;
  }

  for (int kc = ks; kc < ke; kc += 64) {
    __syncthreads();                        // prior MFMA done reading LDS
#pragma unroll
    for (int r4 = 0; r4 < 4; ++r4) {
      __builtin_amdgcn_global_load_lds((gmem_ptr_t)ga[r4], (lds_ptr_t)&As[ldsOff[r4]], 16, 0, 0);
      ga[r4] += 64;
      __builtin_amdgcn_global_load_lds((gmem_ptr_t)gb[r4], (lds_ptr_t)&Bs[ldsOff[r4]], 16, 0, 0);
      gb[r4] += 64;
    }
    __syncthreads();                        // DMA drained (vmcnt(0) at barrier)

#pragma unroll
    for (int s = 0; s < 2; ++s) {
      short8 af[4], bf[4];
#pragma unroll
      for (int mt = 0; mt < 4; ++mt) {
        int rr = wm + mt * 16 + ln;
        int cl = ((s << 2) | q) ^ (rr & 7);
        af[mt] = *(const short8*)&As[rr * 64 + cl * 8];
      }
#pragma unroll
      for (int nt = 0; nt < 4; ++nt) {
        int rr = wn + nt * 16 + ln;
        int cl = ((s << 2) | q) ^ (rr & 7);
        bf[nt] = *(const short8*)&Bs[rr * 64 + cl * 8];
      }
#pragma unroll
      for (int mt = 0; mt < 4; ++mt)
#pragma unroll
        for (int nt = 0; nt < 4; ++nt)
          acc[mt][nt] = __builtin_amdgcn_mfma_f32_16x16x32_bf16(af[mt], bf[nt], acc[mt][nt], 0, 0, 0);
    }
  }

  // Epilogue. D layout: col = lane&15 (n), row = q*4+reg (m)  [m89-verified]
  if (storeMode == 0) {                     // plain row-major store (layer 1 -> H)
#pragma unroll
    for (int mt = 0; mt < 4; ++mt) {
#pragma unroll
      for (int nt = 0; nt < 4; ++nt) {
        int n = bx * 128 + wn + nt * 16 + ln;
        if (n < N) {
          int m0 = by * 128 + wm + mt * 16 + q * 4;
#pragma unroll
          for (int rg = 0; rg < 4; ++rg)
            C[(size_t)(m0 + rg) * ldc + n] = acc[mt][nt][rg];
        }
      }
    }
  } else {                                  // atomic accumulate (layer 2, split-K)
#pragma unroll
    for (int mt = 0; mt < 4; ++mt) {
#pragma unroll
      for (int nt = 0; nt < 4; ++nt) {
        int n = bx * 128 + wn + nt * 16 + ln;
        if (n < N) {
          int m0 = by * 128 + wm + mt * 16 + q * 4;
#pragma unroll
          for (int rg = 0; rg < 4; ++rg)
            atomicAdd(&C[(size_t)(m0 + rg) * ldc + n], acc[mt][nt][rg]);
        }
      }
    }
  }
}

extern "C" void kernel_launch(void* const* d_in, const int* in_sizes, int n_in,
                              void* d_out, int out_size, void* d_ws, size_t ws_size,
                              hipStream_t stream) {
  const float* x   = (const float*)d_in[0];
  const float* bw1 = (const float*)d_in[1];
  const float* sw1 = (const float*)d_in[2];
  const float* sc1 = (const float*)d_in[3];
  const float* bw2 = (const float*)d_in[4];
  const float* sw2 = (const float*)d_in[5];
  const float* sc2 = (const float*)d_in[6];
  float* out = (float*)d_out;

  // Workspace: H (35.7) | A2 (151.5) | A1 (37.7) | W1 (20.1)  = 245.0 MB (proven size)
  // W2 (18.9) aliases A1's region — packed AFTER gemm1 (A1 dead).
  float* H = (float*)d_ws;
  unsigned short* A2 = (unsigned short*)(H + (size_t)T_TOK * HLD);
  unsigned short* A1 = A2 + (size_t)T_TOK * K2P;
  unsigned short* W1 = A1 + (size_t)T_TOK * K1;
  unsigned short* W2 = A1;                               // alias (A1 dead post-gemm1)

  hipMemsetAsync(d_out, 0, (size_t)out_size * sizeof(float), stream);

  // pack_w1 + expand1, one launch (vectorized loads, uint4 stores)
  prep1_kernel<<<PW1_NB + E1_NB, 256, 0, stream>>>(x, bw1, sw1, sc1, A1, W1);

  // Layer 1: H = A1 @ W1'^T. M=4096, N=2049 (rows pad 2176), K=4608. 544 blocks.
  gemm_bt_kernel<<<(O1P / 128) * NBY, 256, 0, stream>>>(
      A1, W1, H, K1, O1, HLD, K1, O1P / 128, 0);

  // W2 into old-A1 region FIRST (A1 dead after gemm1) — its sw2/bw2 traffic must
  // not evict A2 (R6 lesson: +89 MB gemm2 fetch when pack_w2 ran after expand2).
  pack_w2_kernel<<<PW2_NB, 256, 0, stream>>>(bw2, sw2, sc2, W2);

  // A2 from H, written IMMEDIATELY before gemm2 so all 152 MB is L3-warm.
  expand2_kernel<<<dim3((NG2 + 255) / 256, T_TOK), 256, 0, stream>>>(H, A2);

  // Layer 2: out += A2 @ W2'^T. M=4096, N=512, K=18496, split-K 8 -> 1024 blocks.
  gemm_bt_kernel<<<(O2 / 128) * NBY * SPLITS2, 256, 0, stream>>>(
      A2, W2, out, K2P, O2, O2, KLEN2, O2 / 128, 2);
}